// Round 9
// baseline (196.560 us; speedup 1.0000x reference)
//
#include <hip/hip_runtime.h>

// Problem constants (B,C,H,W = 8,64,128,128; K=3)
#define BATCH 8
#define CIN   64
#define HW    16384      // 128*128
#define CK    576        // CIN*K2

typedef __attribute__((ext_vector_type(8))) short bf16x8;
typedef __attribute__((ext_vector_type(4))) float f32x4;
typedef __attribute__((ext_vector_type(2))) float f32x2;

__device__ inline unsigned short f2bf(float f) {
    unsigned int u = __builtin_bit_cast(unsigned int, f);
    u += 0x7FFFu + ((u >> 16) & 1u);          // round-to-nearest-even
    return (unsigned short)(u >> 16);
}
__device__ inline float bf2f(unsigned short u) {
    return __builtin_bit_cast(float, (unsigned)u << 16);
}
__device__ inline f32x2 upk2(unsigned u) {    // two bf16 in a dword -> f32x2
    f32x2 r;
    r[0] = __builtin_bit_cast(float, u << 16);
    r[1] = __builtin_bit_cast(float, u & 0xFFFF0000u);
    return r;
}
#if __has_builtin(__builtin_amdgcn_cvt_pk_bf16_f32)
typedef __attribute__((ext_vector_type(2))) __bf16 bfv2;
__device__ inline unsigned pk2bf(f32x2 s) {   // HW v_cvt_pk_bf16_f32
    bfv2 r = __builtin_amdgcn_cvt_pk_bf16_f32(s[0], s[1]);
    return __builtin_bit_cast(unsigned, r);
}
#else
__device__ inline unsigned pk2bf(f32x2 s) {   // manual RNE fallback
    return (unsigned)f2bf(s[0]) | ((unsigned)f2bf(s[1]) << 16);
}
#endif

// ---------------- ws layout (ushort units) ----------------
// wpack  [18][4][64][8]  deform A-frags      at 0          (36864)
// wcpack [18][2][64][8]  conv A-frags        at 36864      (18432)
// xT     [B][HW][64]     NHWC bf16 input     at 55296      (8388608)

// Fused prep (blocks 0-143) + NCHW->NHWC bf16 transpose (all 2048 blocks).
// A-frag layout (R3-verified): A[m=ot*16+(lane&15)][k=gks*32+(lane>>4)*8+j],
// k-ordering s = tap*64 + c.
__global__ __launch_bounds__(256) void prep_transpose(
        const float* __restrict__ x, const float* __restrict__ ow,
        const float* __restrict__ mw, const float* __restrict__ dw,
        unsigned short* __restrict__ wpack, unsigned short* __restrict__ wcpack,
        unsigned short* __restrict__ xT) {
    int t = threadIdx.x, blk = blockIdx.x;
    // ---- transpose part
    {
        int b = blk & 7, r2 = blk >> 3;
        int h = r2 >> 1, hf = r2 & 1;
        int gx = (hf << 6) + (t & 63);
        int w = t >> 6;
        int pix = (h << 7) + gx;
        const float* __restrict__ xb = x + (b * CIN) * HW + pix;
        bf16x8 lo, hi;
#pragma unroll
        for (int i = 0; i < 8; i++) lo[i] = (short)f2bf(xb[(w * 16 + i) * HW]);
#pragma unroll
        for (int i = 0; i < 8; i++) hi[i] = (short)f2bf(xb[(w * 16 + 8 + i) * HW]);
        unsigned short* dst = xT + ((b * HW + pix) << 6) + w * 16;
        *(bf16x8*)dst = lo;
        *(bf16x8*)(dst + 8) = hi;
    }
    // ---- prep part (first 144 blocks)
    int g = blk * 256 + t;
    if (g < 18 * 4 * 64 * 8) {           // deform weights: dw[o][c][tap]
        int j = g & 7, lane = (g >> 3) & 63, ot = (g >> 9) & 3, gks = g >> 11;
        int o = ot * 16 + (lane & 15);
        int s = gks * 32 + ((lane >> 4) & 3) * 8 + j;
        int c = s & 63, tap = s >> 6;
        wpack[g] = f2bf(dw[o * CK + c * 9 + tap]);
    }
    if (g < 18 * 2 * 64 * 8) {           // conv weights: rows 0-17 ow, 18-26 mw
        int j = g & 7, lane = (g >> 3) & 63, ot = (g >> 9) & 1, gks = g >> 10;
        int o = ot * 16 + (lane & 15);
        int s = gks * 32 + ((lane >> 4) & 3) * 8 + j;
        int c = s & 63, tap = s >> 6;
        float v = 0.f;
        if (o < 18)      v = ow[(o * 64 + c) * 9 + tap];
        else if (o < 27) v = mw[((o - 18) * 64 + c) * 9 + tap];
        wcpack[g] = f2bf(v);
    }
}

// Fused offset/mask conv + deformable conv. Block = 64 px (half row).
// Stage 1: halo tile -> LDS.  Phase A: conv MFMA -> omrow (in buf tail).
// Phase B: bilinear params -> regs (+packed ushort ptab).
// Phase C (no barriers): wave-local coalesced corner gather -> LDS, bfrag, MFMA.
// LDS total 38,272 B -> 4 blocks/CU.
#define OMOFF 14336   // omrow offset inside buf (tile ends at 14256)
__global__ __launch_bounds__(256, 4) void fused_kernel(
        const unsigned short* __restrict__ xT, const unsigned short* __restrict__ wcpack,
        const unsigned short* __restrict__ wpack,
        const float* __restrict__ ob, const float* __restrict__ mb,
        const float* __restrict__ dbv, float* __restrict__ out) {
    // buf regions: Stage1 tile [0,14256) UNION Phase-C gather [0,18560);
    // omrow [OMOFF, OMOFF+2048) — disjoint from tile, dead before gather.
    __shared__ unsigned short buf[18560];      // 37,120 B
    __shared__ unsigned short ptab[576];       //  1,152 B (base|dxb<<14|dyb<<15)

    int t = threadIdx.x;
    int lane = t & 63, pt = t >> 6, quad = lane >> 4, n = lane & 15;
    int blk = blockIdx.x;
    int b = blk & 7, r2 = blk >> 3;
    int h = r2 >> 1, hf = r2 & 1;
    int px0 = hf << 6;
    int pxl = (pt << 4) + n;          // this lane's pixel within the 64-px block
    int gx  = px0 + pxl;

    const unsigned short* __restrict__ xtb = xT + ((b * HW) << 6);
    const short zs = 0;
    const bf16x8 zv = {zs, zs, zs, zs, zs, zs, zs, zs};

    // ========== Stage 1: halo tile (rows h-1..h+1, cols px0-1..px0+64) ==========
    for (int i = t; i < 1584; i += 256) {       // 198 rows x 8 slices
        int s  = i & 7;
        int rc = i >> 3;                        // 0..197
        int r  = rc / 66, col = rc - r * 66;
        int gy  = h - 1 + r;
        int gxc = px0 - 1 + col;
        bf16x8 v = zv;
        if ((unsigned)gy < 128u && (unsigned)gxc < 128u)
            v = *(const bf16x8*)(xtb + (((gy << 7) + gxc) << 6) + (s << 3));
        *(bf16x8*)&buf[rc * 72 + (s << 3)] = v;
    }
    __syncthreads();

    // ========== Phase A: offset/mask conv from LDS tile ==========
    {
        f32x4 acc0 = {0.f, 0.f, 0.f, 0.f}, acc1 = {0.f, 0.f, 0.f, 0.f};
#pragma unroll
        for (int tap = 0; tap < 9; tap++) {
            int r = tap / 3, cm = tap % 3;
            const unsigned short* srcA = &buf[(r * 66 + pxl + cm) * 72];
#pragma unroll
            for (int kk = 0; kk < 2; kk++) {
                bf16x8 bfrag = *(const bf16x8*)(srcA + (kk << 5) + (quad << 3));
                int gks = tap * 2 + kk;
                bf16x8 a0 = *(const bf16x8*)(wcpack + ((gks * 2 + 0) * 64 + lane) * 8);
                bf16x8 a1 = *(const bf16x8*)(wcpack + ((gks * 2 + 1) * 64 + lane) * 8);
                acc0 = __builtin_amdgcn_mfma_f32_16x16x32_bf16(a0, bfrag, acc0, 0, 0, 0);
                acc1 = __builtin_amdgcn_mfma_f32_16x16x32_bf16(a1, bfrag, acc1, 0, 0, 0);
            }
        }
        // epilogue -> omrow (buf tail, disjoint from tile). D[px=lane&15][o=quad*4+r]
        {
            unsigned short p[4];
#pragma unroll
            for (int r = 0; r < 4; r++) p[r] = f2bf(acc0[r] + ob[quad * 4 + r]);
            uint2 u;
            u.x = (unsigned)p[0] | ((unsigned)p[1] << 16);
            u.y = (unsigned)p[2] | ((unsigned)p[3] << 16);
            *(uint2*)&buf[OMOFF + pxl * 32 + quad * 4] = u;
        }
        {
            unsigned short p[4];
#pragma unroll
            for (int r = 0; r < 4; r++) {
                int o = 16 + quad * 4 + r;
                float v = acc1[r];
                if (o < 18) v += ob[o];
                else if (o < 27) { v += mb[o - 18]; v = 1.f / (1.f + __expf(-v)); }
                else v = 0.f;
                p[r] = f2bf(v);
            }
            uint2 u;
            u.x = (unsigned)p[0] | ((unsigned)p[1] << 16);
            u.y = (unsigned)p[2] | ((unsigned)p[3] << 16);
            *(uint2*)&buf[OMOFF + pxl * 32 + 16 + quad * 4] = u;
        }
    }
    __syncthreads();

    // ========== Phase B: bilinear params -> registers (+ptab) ==========
    float w00[9], w01[9], w10[9], w11[9];
#pragma unroll
    for (int k = 0; k < 9; k++) {
        float dy = bf2f(buf[OMOFF + pxl * 32 + 2 * k]);
        float dx = bf2f(buf[OMOFF + pxl * 32 + 2 * k + 1]);
        float mk = bf2f(buf[OMOFF + pxl * 32 + 18 + k]);
        float py  = (float)h  + (float)(k / 3 - 1) + dy;
        float pxx = (float)gx + (float)(k % 3 - 1) + dx;
        float fy = floorf(py), fx = floorf(pxx);
        float ly = py - fy, lx = pxx - fx;
        int y0 = (int)fy, x0 = (int)fx;
        bool y0v = (unsigned)y0 < 128u, y1v = (unsigned)(y0 + 1) < 128u;
        bool x0v = (unsigned)x0 < 128u, x1v = (unsigned)(x0 + 1) < 128u;
        w00[k] = (y0v && x0v) ? (1.f - ly) * (1.f - lx) * mk : 0.f;
        w01[k] = (y0v && x1v) ? (1.f - ly) * lx * mk : 0.f;
        w10[k] = (y1v && x0v) ? ly * (1.f - lx) * mk : 0.f;
        w11[k] = (y1v && x1v) ? ly * lx * mk : 0.f;
        int y0c = min(max(y0, 0), 127), x0c = min(max(x0, 0), 127);
        int dxb = (x0 >= 0 && x0 < 127) ? 1 : 0;
        int dyb = (y0 >= 0 && y0 < 127) ? 1 : 0;
        if (quad == 0)
            ptab[pxl * 9 + k] =
                (unsigned short)(((y0c << 7) + x0c) | (dxb << 14) | (dyb << 15));
    }
    __syncthreads();   // also protects buf(omrow) before gather overwrites

    // ========== Phase C: deform MFMA, barrier-free tap loop ==========
    f32x4 acc[4];
#pragma unroll
    for (int ot = 0; ot < 4; ot++) acc[ot] = (f32x4){0.f, 0.f, 0.f, 0.f};

    unsigned short* gbw = &buf[(pt << 2) * 1160];   // this wave's gather region

#pragma unroll
    for (int tap = 0; tap < 9; tap++) {
        // ---- wave-local coalesced gather: 16 px x 4 corners x 8 slices
#pragma unroll
        for (int i = 0; i < 8; i++) {
            int m = lane + (i << 6);
            int s = m & 7, c = (m >> 3) & 3, pxn = (m >> 5) & 15;
            unsigned p = ptab[((pt << 4) + pxn) * 9 + tap];
            int base = p & 0x3FFF;
            int dxb  = (p >> 14) & 1;
            int dyo  = ((p >> 15) & 1) << 7;
            int row = base + ((-(c & 1)) & dxb) + ((-((c >> 1) & 1)) & dyo);
            bf16x8 v = *(const bf16x8*)(xtb + (row << 6) + (s << 3));
            *(bf16x8*)&gbw[c * 1160 + pxn * 72 + (s << 3)] = v;
        }
        // ---- consume own pixel's corners from LDS
        f32x2 W0 = {w00[tap], w00[tap]}, W1 = {w01[tap], w01[tap]};
        f32x2 W2 = {w10[tap], w10[tap]}, W3 = {w11[tap], w11[tap]};
        const unsigned short* gbr = &gbw[n * 72];
#pragma unroll
        for (int kk = 0; kk < 2; kk++) {
            int co = (kk << 5) + (quad << 3);
            bf16x8 v00 = *(const bf16x8*)(gbr + 0 * 1160 + co);
            bf16x8 v01 = *(const bf16x8*)(gbr + 1 * 1160 + co);
            bf16x8 v10 = *(const bf16x8*)(gbr + 2 * 1160 + co);
            bf16x8 v11 = *(const bf16x8*)(gbr + 3 * 1160 + co);
            const unsigned* u00 = (const unsigned*)&v00;
            const unsigned* u01 = (const unsigned*)&v01;
            const unsigned* u10 = (const unsigned*)&v10;
            const unsigned* u11 = (const unsigned*)&v11;
            bf16x8 bfrag;
            unsigned* bu = (unsigned*)&bfrag;
#pragma unroll
            for (int jj = 0; jj < 4; jj++) {
                f32x2 s2 = upk2(u00[jj]) * W0 + upk2(u01[jj]) * W1
                         + upk2(u10[jj]) * W2 + upk2(u11[jj]) * W3;
                bu[jj] = pk2bf(s2);
            }
            int gks = tap * 2 + kk;
#pragma unroll
            for (int ot = 0; ot < 4; ot++) {
                bf16x8 af = *(const bf16x8*)(wpack + ((gks * 4 + ot) * 64 + lane) * 8);
                acc[ot] = __builtin_amdgcn_mfma_f32_16x16x32_bf16(af, bfrag, acc[ot], 0, 0, 0);
            }
        }
    }

    // ---- epilogue: D col(lane&15)=px, row = ot*16 + quad*4 + r = o
    int opix = (h << 7) + px0 + (pt << 4) + n;
#pragma unroll
    for (int ot = 0; ot < 4; ot++) {
#pragma unroll
        for (int r = 0; r < 4; r++) {
            int o = ot * 16 + quad * 4 + r;
            out[(b * 64 + o) * HW + opix] = acc[ot][r] + dbv[o];
        }
    }
}

extern "C" void kernel_launch(void* const* d_in, const int* in_sizes, int n_in,
                              void* d_out, int out_size, void* d_ws, size_t ws_size,
                              hipStream_t stream) {
    const float* x   = (const float*)d_in[0];
    const float* ow  = (const float*)d_in[1];
    const float* ob  = (const float*)d_in[2];
    const float* mw  = (const float*)d_in[3];
    const float* mb  = (const float*)d_in[4];
    const float* dw  = (const float*)d_in[5];
    const float* dbv = (const float*)d_in[6];
    float* out = (float*)d_out;

    unsigned short* wpack  = (unsigned short*)d_ws;          // 36864
    unsigned short* wcpack = wpack + 36864;                  // 18432
    unsigned short* xT     = wpack + 55296;                  // 8388608

    prep_transpose<<<2048, 256, 0, stream>>>(x, ow, mw, dw, wpack, wcpack, xT);
    fused_kernel<<<2048, 256, 0, stream>>>(xT, wcpack, wpack, ob, mb, dbv, out);
}

// Round 10
// 182.788 us; speedup vs baseline: 1.0753x; 1.0753x over previous
//
#include <hip/hip_runtime.h>

// Problem constants (B,C,H,W = 8,64,128,128; K=3)
#define BATCH 8
#define CIN   64
#define HW    16384      // 128*128
#define CK    576        // CIN*K2

typedef __attribute__((ext_vector_type(8))) short bf16x8;
typedef __attribute__((ext_vector_type(4))) float f32x4;
typedef __attribute__((ext_vector_type(2))) float f32x2;

__device__ inline unsigned short f2bf(float f) {
    unsigned int u = __builtin_bit_cast(unsigned int, f);
    u += 0x7FFFu + ((u >> 16) & 1u);          // round-to-nearest-even
    return (unsigned short)(u >> 16);
}
__device__ inline float bf2f(unsigned short u) {
    return __builtin_bit_cast(float, (unsigned)u << 16);
}
__device__ inline f32x2 upk2(unsigned u) {    // two bf16 in a dword -> f32x2
    f32x2 r;
    r[0] = __builtin_bit_cast(float, u << 16);
    r[1] = __builtin_bit_cast(float, u & 0xFFFF0000u);
    return r;
}
#if __has_builtin(__builtin_amdgcn_cvt_pk_bf16_f32)
typedef __attribute__((ext_vector_type(2))) __bf16 bfv2;
__device__ inline unsigned pk2bf(f32x2 s) {   // HW v_cvt_pk_bf16_f32
    bfv2 r = __builtin_amdgcn_cvt_pk_bf16_f32(s[0], s[1]);
    return __builtin_bit_cast(unsigned, r);
}
#else
__device__ inline unsigned pk2bf(f32x2 s) {   // manual RNE fallback
    return (unsigned)f2bf(s[0]) | ((unsigned)f2bf(s[1]) << 16);
}
#endif

// ---------------- ws layout (ushort units) ----------------
// wpack  [18][4][64][8]  deform A-frags      at 0          (36864)
// wcpack [18][2][64][8]  conv A-frags        at 36864      (18432)
// xT     [B][HW][64]     NHWC bf16 input     at 55296      (8388608)

// Fused prep (blocks 0-143) + NCHW->NHWC bf16 transpose (all 2048 blocks).
// A-frag layout (R3-verified): A[m=ot*16+(lane&15)][k=gks*32+(lane>>4)*8+j],
// k-ordering s = tap*64 + c.
__global__ __launch_bounds__(256) void prep_transpose(
        const float* __restrict__ x, const float* __restrict__ ow,
        const float* __restrict__ mw, const float* __restrict__ dw,
        unsigned short* __restrict__ wpack, unsigned short* __restrict__ wcpack,
        unsigned short* __restrict__ xT) {
    int t = threadIdx.x, blk = blockIdx.x;
    // ---- transpose part
    {
        int b = blk & 7, r2 = blk >> 3;
        int h = r2 >> 1, hf = r2 & 1;
        int gx = (hf << 6) + (t & 63);
        int w = t >> 6;
        int pix = (h << 7) + gx;
        const float* __restrict__ xb = x + (b * CIN) * HW + pix;
        bf16x8 lo, hi;
#pragma unroll
        for (int i = 0; i < 8; i++) lo[i] = (short)f2bf(xb[(w * 16 + i) * HW]);
#pragma unroll
        for (int i = 0; i < 8; i++) hi[i] = (short)f2bf(xb[(w * 16 + 8 + i) * HW]);
        unsigned short* dst = xT + ((b * HW + pix) << 6) + w * 16;
        *(bf16x8*)dst = lo;
        *(bf16x8*)(dst + 8) = hi;
    }
    // ---- prep part (first 144 blocks)
    int g = blk * 256 + t;
    if (g < 18 * 4 * 64 * 8) {           // deform weights: dw[o][c][tap]
        int j = g & 7, lane = (g >> 3) & 63, ot = (g >> 9) & 3, gks = g >> 11;
        int o = ot * 16 + (lane & 15);
        int s = gks * 32 + ((lane >> 4) & 3) * 8 + j;
        int c = s & 63, tap = s >> 6;
        wpack[g] = f2bf(dw[o * CK + c * 9 + tap]);
    }
    if (g < 18 * 2 * 64 * 8) {           // conv weights: rows 0-17 ow, 18-26 mw
        int j = g & 7, lane = (g >> 3) & 63, ot = (g >> 9) & 1, gks = g >> 10;
        int o = ot * 16 + (lane & 15);
        int s = gks * 32 + ((lane >> 4) & 3) * 8 + j;
        int c = s & 63, tap = s >> 6;
        float v = 0.f;
        if (o < 18)      v = ow[(o * 64 + c) * 9 + tap];
        else if (o < 27) v = mw[((o - 18) * 64 + c) * 9 + tap];
        wcpack[g] = f2bf(v);
    }
}

// Fused offset/mask conv + deformable conv. Block = 64 px (half row).
// Stage 1: halo tile -> LDS.  Phase A: conv MFMA -> omrow (in buf tail).
// Phase B: bilinear params -> regs (+packed ushort ptab).
// Phase C (no barriers): wave-local coalesced corner gather -> LDS, bfrag, MFMA.
// LDS total 38,272 B -> 4 blocks/CU at runtime.
// NOTE: __launch_bounds__ min-waves stays at 3 — forcing 4 makes LLVM clamp
// VGPR 84->64 and spill to scratch (R9: WRITE_SIZE doubled, +30 us).
#define OMOFF 14336   // omrow offset inside buf (tile ends at 14256)
__global__ __launch_bounds__(256, 3) void fused_kernel(
        const unsigned short* __restrict__ xT, const unsigned short* __restrict__ wcpack,
        const unsigned short* __restrict__ wpack,
        const float* __restrict__ ob, const float* __restrict__ mb,
        const float* __restrict__ dbv, float* __restrict__ out) {
    // buf regions: Stage1 tile [0,14256) UNION Phase-C gather [0,18560);
    // omrow [OMOFF, OMOFF+2048) — disjoint from tile, dead before gather.
    __shared__ unsigned short buf[18560];      // 37,120 B
    __shared__ unsigned short ptab[576];       //  1,152 B (base|dxb<<14|dyb<<15)

    int t = threadIdx.x;
    int lane = t & 63, pt = t >> 6, quad = lane >> 4, n = lane & 15;
    int blk = blockIdx.x;
    int b = blk & 7, r2 = blk >> 3;
    int h = r2 >> 1, hf = r2 & 1;
    int px0 = hf << 6;
    int pxl = (pt << 4) + n;          // this lane's pixel within the 64-px block
    int gx  = px0 + pxl;

    const unsigned short* __restrict__ xtb = xT + ((b * HW) << 6);
    const short zs = 0;
    const bf16x8 zv = {zs, zs, zs, zs, zs, zs, zs, zs};

    // ========== Stage 1: halo tile (rows h-1..h+1, cols px0-1..px0+64) ==========
    for (int i = t; i < 1584; i += 256) {       // 198 rows x 8 slices
        int s  = i & 7;
        int rc = i >> 3;                        // 0..197
        int r  = rc / 66, col = rc - r * 66;
        int gy  = h - 1 + r;
        int gxc = px0 - 1 + col;
        bf16x8 v = zv;
        if ((unsigned)gy < 128u && (unsigned)gxc < 128u)
            v = *(const bf16x8*)(xtb + (((gy << 7) + gxc) << 6) + (s << 3));
        *(bf16x8*)&buf[rc * 72 + (s << 3)] = v;
    }
    __syncthreads();

    // ========== Phase A: offset/mask conv from LDS tile ==========
    {
        f32x4 acc0 = {0.f, 0.f, 0.f, 0.f}, acc1 = {0.f, 0.f, 0.f, 0.f};
#pragma unroll
        for (int tap = 0; tap < 9; tap++) {
            int r = tap / 3, cm = tap % 3;
            const unsigned short* srcA = &buf[(r * 66 + pxl + cm) * 72];
#pragma unroll
            for (int kk = 0; kk < 2; kk++) {
                bf16x8 bfrag = *(const bf16x8*)(srcA + (kk << 5) + (quad << 3));
                int gks = tap * 2 + kk;
                bf16x8 a0 = *(const bf16x8*)(wcpack + ((gks * 2 + 0) * 64 + lane) * 8);
                bf16x8 a1 = *(const bf16x8*)(wcpack + ((gks * 2 + 1) * 64 + lane) * 8);
                acc0 = __builtin_amdgcn_mfma_f32_16x16x32_bf16(a0, bfrag, acc0, 0, 0, 0);
                acc1 = __builtin_amdgcn_mfma_f32_16x16x32_bf16(a1, bfrag, acc1, 0, 0, 0);
            }
        }
        // epilogue -> omrow (buf tail, disjoint from tile). D[px=lane&15][o=quad*4+r]
        {
            unsigned short p[4];
#pragma unroll
            for (int r = 0; r < 4; r++) p[r] = f2bf(acc0[r] + ob[quad * 4 + r]);
            uint2 u;
            u.x = (unsigned)p[0] | ((unsigned)p[1] << 16);
            u.y = (unsigned)p[2] | ((unsigned)p[3] << 16);
            *(uint2*)&buf[OMOFF + pxl * 32 + quad * 4] = u;
        }
        {
            unsigned short p[4];
#pragma unroll
            for (int r = 0; r < 4; r++) {
                int o = 16 + quad * 4 + r;
                float v = acc1[r];
                if (o < 18) v += ob[o];
                else if (o < 27) { v += mb[o - 18]; v = 1.f / (1.f + __expf(-v)); }
                else v = 0.f;
                p[r] = f2bf(v);
            }
            uint2 u;
            u.x = (unsigned)p[0] | ((unsigned)p[1] << 16);
            u.y = (unsigned)p[2] | ((unsigned)p[3] << 16);
            *(uint2*)&buf[OMOFF + pxl * 32 + 16 + quad * 4] = u;
        }
    }
    __syncthreads();

    // ========== Phase B: bilinear params -> registers (+ptab) ==========
    float w00[9], w01[9], w10[9], w11[9];
#pragma unroll
    for (int k = 0; k < 9; k++) {
        float dy = bf2f(buf[OMOFF + pxl * 32 + 2 * k]);
        float dx = bf2f(buf[OMOFF + pxl * 32 + 2 * k + 1]);
        float mk = bf2f(buf[OMOFF + pxl * 32 + 18 + k]);
        float py  = (float)h  + (float)(k / 3 - 1) + dy;
        float pxx = (float)gx + (float)(k % 3 - 1) + dx;
        float fy = floorf(py), fx = floorf(pxx);
        float ly = py - fy, lx = pxx - fx;
        int y0 = (int)fy, x0 = (int)fx;
        bool y0v = (unsigned)y0 < 128u, y1v = (unsigned)(y0 + 1) < 128u;
        bool x0v = (unsigned)x0 < 128u, x1v = (unsigned)(x0 + 1) < 128u;
        w00[k] = (y0v && x0v) ? (1.f - ly) * (1.f - lx) * mk : 0.f;
        w01[k] = (y0v && x1v) ? (1.f - ly) * lx * mk : 0.f;
        w10[k] = (y1v && x0v) ? ly * (1.f - lx) * mk : 0.f;
        w11[k] = (y1v && x1v) ? ly * lx * mk : 0.f;
        int y0c = min(max(y0, 0), 127), x0c = min(max(x0, 0), 127);
        int dxb = (x0 >= 0 && x0 < 127) ? 1 : 0;
        int dyb = (y0 >= 0 && y0 < 127) ? 1 : 0;
        if (quad == 0)
            ptab[pxl * 9 + k] =
                (unsigned short)(((y0c << 7) + x0c) | (dxb << 14) | (dyb << 15));
    }
    __syncthreads();   // also protects buf(omrow) before gather overwrites

    // ========== Phase C: deform MFMA, barrier-free tap loop ==========
    f32x4 acc[4];
#pragma unroll
    for (int ot = 0; ot < 4; ot++) acc[ot] = (f32x4){0.f, 0.f, 0.f, 0.f};

    unsigned short* gbw = &buf[(pt << 2) * 1160];   // this wave's gather region

#pragma unroll
    for (int tap = 0; tap < 9; tap++) {
        // ---- wave-local coalesced gather: 16 px x 4 corners x 8 slices
#pragma unroll
        for (int i = 0; i < 8; i++) {
            int m = lane + (i << 6);
            int s = m & 7, c = (m >> 3) & 3, pxn = (m >> 5) & 15;
            unsigned p = ptab[((pt << 4) + pxn) * 9 + tap];
            int base = p & 0x3FFF;
            int dxb  = (p >> 14) & 1;
            int dyo  = ((p >> 15) & 1) << 7;
            int row = base + ((-(c & 1)) & dxb) + ((-((c >> 1) & 1)) & dyo);
            bf16x8 v = *(const bf16x8*)(xtb + (row << 6) + (s << 3));
            *(bf16x8*)&gbw[c * 1160 + pxn * 72 + (s << 3)] = v;
        }
        // ---- consume own pixel's corners from LDS
        f32x2 W0 = {w00[tap], w00[tap]}, W1 = {w01[tap], w01[tap]};
        f32x2 W2 = {w10[tap], w10[tap]}, W3 = {w11[tap], w11[tap]};
        const unsigned short* gbr = &gbw[n * 72];
#pragma unroll
        for (int kk = 0; kk < 2; kk++) {
            int co = (kk << 5) + (quad << 3);
            bf16x8 v00 = *(const bf16x8*)(gbr + 0 * 1160 + co);
            bf16x8 v01 = *(const bf16x8*)(gbr + 1 * 1160 + co);
            bf16x8 v10 = *(const bf16x8*)(gbr + 2 * 1160 + co);
            bf16x8 v11 = *(const bf16x8*)(gbr + 3 * 1160 + co);
            const unsigned* u00 = (const unsigned*)&v00;
            const unsigned* u01 = (const unsigned*)&v01;
            const unsigned* u10 = (const unsigned*)&v10;
            const unsigned* u11 = (const unsigned*)&v11;
            bf16x8 bfrag;
            unsigned* bu = (unsigned*)&bfrag;
#pragma unroll
            for (int jj = 0; jj < 4; jj++) {
                f32x2 s2 = upk2(u00[jj]) * W0 + upk2(u01[jj]) * W1
                         + upk2(u10[jj]) * W2 + upk2(u11[jj]) * W3;
                bu[jj] = pk2bf(s2);
            }
            int gks = tap * 2 + kk;
#pragma unroll
            for (int ot = 0; ot < 4; ot++) {
                bf16x8 af = *(const bf16x8*)(wpack + ((gks * 4 + ot) * 64 + lane) * 8);
                acc[ot] = __builtin_amdgcn_mfma_f32_16x16x32_bf16(af, bfrag, acc[ot], 0, 0, 0);
            }
        }
    }

    // ---- epilogue: D col(lane&15)=px, row = ot*16 + quad*4 + r = o
    int opix = (h << 7) + px0 + (pt << 4) + n;
#pragma unroll
    for (int ot = 0; ot < 4; ot++) {
#pragma unroll
        for (int r = 0; r < 4; r++) {
            int o = ot * 16 + quad * 4 + r;
            out[(b * 64 + o) * HW + opix] = acc[ot][r] + dbv[o];
        }
    }
}

extern "C" void kernel_launch(void* const* d_in, const int* in_sizes, int n_in,
                              void* d_out, int out_size, void* d_ws, size_t ws_size,
                              hipStream_t stream) {
    const float* x   = (const float*)d_in[0];
    const float* ow  = (const float*)d_in[1];
    const float* ob  = (const float*)d_in[2];
    const float* mw  = (const float*)d_in[3];
    const float* mb  = (const float*)d_in[4];
    const float* dw  = (const float*)d_in[5];
    const float* dbv = (const float*)d_in[6];
    float* out = (float*)d_out;

    unsigned short* wpack  = (unsigned short*)d_ws;          // 36864
    unsigned short* wcpack = wpack + 36864;                  // 18432
    unsigned short* xT     = wpack + 55296;                  // 8388608

    prep_transpose<<<2048, 256, 0, stream>>>(x, ow, mw, dw, wpack, wcpack, xT);
    fused_kernel<<<2048, 256, 0, stream>>>(xT, wcpack, wpack, ob, mb, dbv, out);
}

// Round 11
// 160.053 us; speedup vs baseline: 1.2281x; 1.1420x over previous
//
#include <hip/hip_runtime.h>

// Problem constants (B,C,H,W = 8,64,128,128; K=3)
#define BATCH 8
#define CIN   64
#define HW    16384      // 128*128
#define CK    576        // CIN*K2

typedef __attribute__((ext_vector_type(8))) short bf16x8;
typedef __attribute__((ext_vector_type(4))) float f32x4;
typedef __attribute__((ext_vector_type(2))) float f32x2;

__device__ inline unsigned short f2bf(float f) {
    unsigned int u = __builtin_bit_cast(unsigned int, f);
    u += 0x7FFFu + ((u >> 16) & 1u);          // round-to-nearest-even
    return (unsigned short)(u >> 16);
}
__device__ inline float bf2f(unsigned short u) {
    return __builtin_bit_cast(float, (unsigned)u << 16);
}
__device__ inline f32x2 upk2(unsigned u) {    // two bf16 in a dword -> f32x2
    f32x2 r;
    r[0] = __builtin_bit_cast(float, u << 16);
    r[1] = __builtin_bit_cast(float, u & 0xFFFF0000u);
    return r;
}
__device__ inline unsigned pk2bf(f32x2 s) {   // manual RNE pack (R8 codegen)
    return (unsigned)f2bf(s[0]) | ((unsigned)f2bf(s[1]) << 16);
}

// ---------------- ws layout (ushort units) ----------------
// wpack  [18][4][64][8]  deform A-frags      at 0          (36864)
// wcpack [18][2][64][8]  conv A-frags        at 36864      (18432)
// xT     [B][HW][64]     NHWC bf16 input     at 55296      (8388608)

// Fused prep (blocks 0-143) + NCHW->NHWC bf16 transpose (all 2048 blocks).
__global__ __launch_bounds__(256) void prep_transpose(
        const float* __restrict__ x, const float* __restrict__ ow,
        const float* __restrict__ mw, const float* __restrict__ dw,
        unsigned short* __restrict__ wpack, unsigned short* __restrict__ wcpack,
        unsigned short* __restrict__ xT) {
    int t = threadIdx.x, blk = blockIdx.x;
    // ---- transpose part
    {
        int b = blk & 7, r2 = blk >> 3;
        int h = r2 >> 1, hf = r2 & 1;
        int gx = (hf << 6) + (t & 63);
        int w = t >> 6;
        int pix = (h << 7) + gx;
        const float* __restrict__ xb = x + (b * CIN) * HW + pix;
        bf16x8 lo, hi;
#pragma unroll
        for (int i = 0; i < 8; i++) lo[i] = (short)f2bf(xb[(w * 16 + i) * HW]);
#pragma unroll
        for (int i = 0; i < 8; i++) hi[i] = (short)f2bf(xb[(w * 16 + 8 + i) * HW]);
        unsigned short* dst = xT + ((b * HW + pix) << 6) + w * 16;
        *(bf16x8*)dst = lo;
        *(bf16x8*)(dst + 8) = hi;
    }
    // ---- prep part (first 144 blocks)
    int g = blk * 256 + t;
    if (g < 18 * 4 * 64 * 8) {           // deform weights: dw[o][c][tap]
        int j = g & 7, lane = (g >> 3) & 63, ot = (g >> 9) & 3, gks = g >> 11;
        int o = ot * 16 + (lane & 15);
        int s = gks * 32 + ((lane >> 4) & 3) * 8 + j;
        int c = s & 63, tap = s >> 6;
        wpack[g] = f2bf(dw[o * CK + c * 9 + tap]);
    }
    if (g < 18 * 2 * 64 * 8) {           // conv weights: rows 0-17 ow, 18-26 mw
        int j = g & 7, lane = (g >> 3) & 63, ot = (g >> 9) & 1, gks = g >> 10;
        int o = ot * 16 + (lane & 15);
        int s = gks * 32 + ((lane >> 4) & 3) * 8 + j;
        int c = s & 63, tap = s >> 6;
        float v = 0.f;
        if (o < 18)      v = ow[(o * 64 + c) * 9 + tap];
        else if (o < 27) v = mw[((o - 18) * 64 + c) * 9 + tap];
        wcpack[g] = f2bf(v);
    }
}

// Fused offset/mask conv + deformable conv. Block = 64 px (half row).
// R8 structure + Phase-C 1-tap register prefetch pipeline; bilinear weights
// in LDS wtab (frees ~36 VGPRs so the prefetch doesn't spill — R9 lesson).
// LDS 52,736 B -> 3 blocks/CU.
__global__ __launch_bounds__(256, 3) void fused_kernel(
        const unsigned short* __restrict__ xT, const unsigned short* __restrict__ wcpack,
        const unsigned short* __restrict__ wpack,
        const float* __restrict__ ob, const float* __restrict__ mb,
        const float* __restrict__ dbv, float* __restrict__ out) {
    __shared__ unsigned short buf[18560];      // 37,120 B: tile UNION gather
    __shared__ unsigned short omrow[2048];     //  4,096 B
    __shared__ int ptab[576];                  //  2,304 B
    __shared__ float wtab[2304];               //  9,216 B: [px][tap][4 weights]

    int t = threadIdx.x;
    int lane = t & 63, pt = t >> 6, quad = lane >> 4, n = lane & 15;
    int blk = blockIdx.x;
    int b = blk & 7, r2 = blk >> 3;
    int h = r2 >> 1, hf = r2 & 1;
    int px0 = hf << 6;
    int pxl = (pt << 4) + n;          // this lane's pixel within the 64-px block
    int gx  = px0 + pxl;

    const unsigned short* __restrict__ xtb = xT + ((b * HW) << 6);
    const short zs = 0;
    const bf16x8 zv = {zs, zs, zs, zs, zs, zs, zs, zs};

    // ========== Stage 1: halo tile (rows h-1..h+1, cols px0-1..px0+64) ==========
    for (int i = t; i < 1584; i += 256) {       // 198 rows x 8 slices
        int s  = i & 7;
        int rc = i >> 3;                        // 0..197
        int r  = rc / 66, col = rc - r * 66;
        int gy  = h - 1 + r;
        int gxc = px0 - 1 + col;
        bf16x8 v = zv;
        if ((unsigned)gy < 128u && (unsigned)gxc < 128u)
            v = *(const bf16x8*)(xtb + (((gy << 7) + gxc) << 6) + (s << 3));
        *(bf16x8*)&buf[rc * 72 + (s << 3)] = v;
    }
    __syncthreads();

    // ========== Phase A: offset/mask conv from LDS tile ==========
    {
        f32x4 acc0 = {0.f, 0.f, 0.f, 0.f}, acc1 = {0.f, 0.f, 0.f, 0.f};
#pragma unroll
        for (int tap = 0; tap < 9; tap++) {
            int r = tap / 3, cm = tap % 3;
            const unsigned short* srcA = &buf[(r * 66 + pxl + cm) * 72];
#pragma unroll
            for (int kk = 0; kk < 2; kk++) {
                bf16x8 bfrag = *(const bf16x8*)(srcA + (kk << 5) + (quad << 3));
                int gks = tap * 2 + kk;
                bf16x8 a0 = *(const bf16x8*)(wcpack + ((gks * 2 + 0) * 64 + lane) * 8);
                bf16x8 a1 = *(const bf16x8*)(wcpack + ((gks * 2 + 1) * 64 + lane) * 8);
                acc0 = __builtin_amdgcn_mfma_f32_16x16x32_bf16(a0, bfrag, acc0, 0, 0, 0);
                acc1 = __builtin_amdgcn_mfma_f32_16x16x32_bf16(a1, bfrag, acc1, 0, 0, 0);
            }
        }
        // epilogue -> omrow LDS. D[px=lane&15][o=quad*4+r] (+16 for acc1)
        {
            unsigned short p[4];
#pragma unroll
            for (int r = 0; r < 4; r++) p[r] = f2bf(acc0[r] + ob[quad * 4 + r]);
            uint2 u;
            u.x = (unsigned)p[0] | ((unsigned)p[1] << 16);
            u.y = (unsigned)p[2] | ((unsigned)p[3] << 16);
            *(uint2*)&omrow[pxl * 32 + quad * 4] = u;
        }
        {
            unsigned short p[4];
#pragma unroll
            for (int r = 0; r < 4; r++) {
                int o = 16 + quad * 4 + r;
                float v = acc1[r];
                if (o < 18) v += ob[o];
                else if (o < 27) { v += mb[o - 18]; v = 1.f / (1.f + __expf(-v)); }
                else v = 0.f;
                p[r] = f2bf(v);
            }
            uint2 u;
            u.x = (unsigned)p[0] | ((unsigned)p[1] << 16);
            u.y = (unsigned)p[2] | ((unsigned)p[3] << 16);
            *(uint2*)&omrow[pxl * 32 + 16 + quad * 4] = u;
        }
    }
    __syncthreads();

    // ========== Phase B: bilinear params -> wtab/ptab LDS ==========
#pragma unroll
    for (int k = 0; k < 9; k++) {
        float dy = bf2f(omrow[pxl * 32 + 2 * k]);
        float dx = bf2f(omrow[pxl * 32 + 2 * k + 1]);
        float mk = bf2f(omrow[pxl * 32 + 18 + k]);
        float py  = (float)h  + (float)(k / 3 - 1) + dy;
        float pxx = (float)gx + (float)(k % 3 - 1) + dx;
        float fy = floorf(py), fx = floorf(pxx);
        float ly = py - fy, lx = pxx - fx;
        int y0 = (int)fy, x0 = (int)fx;
        bool y0v = (unsigned)y0 < 128u, y1v = (unsigned)(y0 + 1) < 128u;
        bool x0v = (unsigned)x0 < 128u, x1v = (unsigned)(x0 + 1) < 128u;
        f32x4 wv;
        wv[0] = (y0v && x0v) ? (1.f - ly) * (1.f - lx) * mk : 0.f;
        wv[1] = (y0v && x1v) ? (1.f - ly) * lx * mk : 0.f;
        wv[2] = (y1v && x0v) ? ly * (1.f - lx) * mk : 0.f;
        wv[3] = (y1v && x1v) ? ly * lx * mk : 0.f;
        int y0c = min(max(y0, 0), 127), x0c = min(max(x0, 0), 127);
        int dxb = (x0 >= 0 && x0 < 127) ? 1 : 0;
        int dyb = (y0 >= 0 && y0 < 127) ? 1 : 0;
        if (quad == 0) {
            ptab[pxl * 9 + k] = ((y0c << 7) + x0c) | (dxb << 14) | (dyb << 15);
            *(f32x4*)&wtab[(pxl * 9 + k) * 4] = wv;
        }
    }
    __syncthreads();

    // ========== Phase C: deform MFMA, 1-tap register prefetch ==========
    f32x4 acc[4];
#pragma unroll
    for (int ot = 0; ot < 4; ot++) acc[ot] = (f32x4){0.f, 0.f, 0.f, 0.f};

    unsigned short* gbw = &buf[(pt << 2) * 1160];   // this wave's gather region
    // lane-constant gather components: m = lane + i*64
    //   s = m&7 = lane&7;  c = (m>>3)&3 = (lane>>3)&3;  pxn = (lane>>5) + 2*i
    int soff   = (lane & 7) << 3;
    int c2     = (lane >> 3) & 3;
    int cm1    = -(c2 & 1);
    int cm2    = -((c2 >> 1) & 1);
    int pxnb   = lane >> 5;
    int pibase = (pt << 4) * 9;
    int gwbase = c2 * 1160 + soff;
    int setbase = pxl * 9;

    bf16x8 pf[8];
#pragma unroll
    for (int i = 0; i < 8; i++) {       // prologue: tap 0 loads
        int p = ptab[pibase + (pxnb + 2 * i) * 9];
        int row = (p & 0x3FFF) + (cm1 & ((p >> 14) & 1)) + (cm2 & (((p >> 15) & 1) << 7));
        pf[i] = *(const bf16x8*)(xtb + (row << 6) + soff);
    }

#pragma unroll
    for (int tap = 0; tap < 9; tap++) {
        // issue next tap's loads first (latency hidden behind this tap's compute)
        bf16x8 nf[8];
        if (tap < 8) {
#pragma unroll
            for (int i = 0; i < 8; i++) {
                int p = ptab[pibase + (pxnb + 2 * i) * 9 + tap + 1];
                int row = (p & 0x3FFF) + (cm1 & ((p >> 14) & 1)) + (cm2 & (((p >> 15) & 1) << 7));
                nf[i] = *(const bf16x8*)(xtb + (row << 6) + soff);
            }
        }
        // stash current tap's gather to LDS
#pragma unroll
        for (int i = 0; i < 8; i++)
            *(bf16x8*)&gbw[gwbase + (pxnb + 2 * i) * 72] = pf[i];

        f32x4 wv = *(const f32x4*)&wtab[(setbase + tap) * 4];
        f32x2 W0 = {wv[0], wv[0]}, W1 = {wv[1], wv[1]};
        f32x2 W2 = {wv[2], wv[2]}, W3 = {wv[3], wv[3]};
        const unsigned short* gbr = &gbw[n * 72];
#pragma unroll
        for (int kk = 0; kk < 2; kk++) {
            int co = (kk << 5) + (quad << 3);
            bf16x8 v00 = *(const bf16x8*)(gbr + 0 * 1160 + co);
            bf16x8 v01 = *(const bf16x8*)(gbr + 1 * 1160 + co);
            bf16x8 v10 = *(const bf16x8*)(gbr + 2 * 1160 + co);
            bf16x8 v11 = *(const bf16x8*)(gbr + 3 * 1160 + co);
            const unsigned* u00 = (const unsigned*)&v00;
            const unsigned* u01 = (const unsigned*)&v01;
            const unsigned* u10 = (const unsigned*)&v10;
            const unsigned* u11 = (const unsigned*)&v11;
            bf16x8 bfrag;
            unsigned* bu = (unsigned*)&bfrag;
#pragma unroll
            for (int jj = 0; jj < 4; jj++) {
                f32x2 s2 = upk2(u00[jj]) * W0 + upk2(u01[jj]) * W1
                         + upk2(u10[jj]) * W2 + upk2(u11[jj]) * W3;
                bu[jj] = pk2bf(s2);
            }
            int gks = tap * 2 + kk;
#pragma unroll
            for (int ot = 0; ot < 4; ot++) {
                bf16x8 af = *(const bf16x8*)(wpack + ((gks * 4 + ot) * 64 + lane) * 8);
                acc[ot] = __builtin_amdgcn_mfma_f32_16x16x32_bf16(af, bfrag, acc[ot], 0, 0, 0);
            }
        }
        if (tap < 8) {
#pragma unroll
            for (int i = 0; i < 8; i++) pf[i] = nf[i];
        }
    }

    // ---- epilogue: D col(lane&15)=px, row = ot*16 + quad*4 + r = o
    int opix = (h << 7) + px0 + (pt << 4) + n;
#pragma unroll
    for (int ot = 0; ot < 4; ot++) {
#pragma unroll
        for (int r = 0; r < 4; r++) {
            int o = ot * 16 + quad * 4 + r;
            out[(b * 64 + o) * HW + opix] = acc[ot][r] + dbv[o];
        }
    }
}

extern "C" void kernel_launch(void* const* d_in, const int* in_sizes, int n_in,
                              void* d_out, int out_size, void* d_ws, size_t ws_size,
                              hipStream_t stream) {
    const float* x   = (const float*)d_in[0];
    const float* ow  = (const float*)d_in[1];
    const float* ob  = (const float*)d_in[2];
    const float* mw  = (const float*)d_in[3];
    const float* mb  = (const float*)d_in[4];
    const float* dw  = (const float*)d_in[5];
    const float* dbv = (const float*)d_in[6];
    float* out = (float*)d_out;

    unsigned short* wpack  = (unsigned short*)d_ws;          // 36864
    unsigned short* wcpack = wpack + 36864;                  // 18432
    unsigned short* xT     = wpack + 55296;                  // 8388608

    prep_transpose<<<2048, 256, 0, stream>>>(x, ow, mw, dw, wpack, wcpack, xT);
    fused_kernel<<<2048, 256, 0, stream>>>(xT, wcpack, wpack, ob, mb, dbv, out);
}